// Round 3
// baseline (221.221 us; speedup 1.0000x reference)
//
#include <hip/hip_runtime.h>
#include <hip/hip_bf16.h>

// NA Spatial MSA, fused:  out = attn @ (xw @ (Wv@Wo)) + bo
// R3: persistent pipeline. Grid 512 blocks x 8 windows, LDS double-buffered
// (2x40KB), next-window loads prefetched to regs during current compute (T14),
// raw s_barrier without vmcnt drain (T4), GEMM2 B-frags built in-register from
// GEMM1 accumulators via pack + shfl_xor(32) (no zT LDS round-trip).

typedef __bf16 bf16x8 __attribute__((ext_vector_type(8)));
typedef __bf16 bf16x4 __attribute__((ext_vector_type(4)));
typedef float  f32x16 __attribute__((ext_vector_type(16)));
typedef float  f32x4  __attribute__((ext_vector_type(4)));
typedef unsigned int uint;
typedef uint   uint4v __attribute__((ext_vector_type(4)));

#define MFMA32(a, b, c) __builtin_amdgcn_mfma_f32_32x32x16_bf16(a, b, c, 0, 0, 0)

// ---------------- Stage 0: WT = (Wv @ Wo)^T in bf16 ----------------
__global__ void wfuse_kernel(const float* __restrict__ Wv,
                             const float* __restrict__ Wo,
                             __bf16* __restrict__ WT) {
  const int n = blockIdx.x;    // output channel (col of W)
  const int k = threadIdx.x;   // input channel  (row of W)
  const float* wvrow = Wv + k * 256;
  float acc = 0.f;
#pragma unroll 4
  for (int j = 0; j < 256; j += 4) {
    f32x4 wv = *(const f32x4*)(wvrow + j);
    acc += wv.x * Wo[(j + 0) * 256 + n];
    acc += wv.y * Wo[(j + 1) * 256 + n];
    acc += wv.z * Wo[(j + 2) * 256 + n];
    acc += wv.w * Wo[(j + 3) * 256 + n];
  }
  WT[n * 256 + k] = (__bf16)acc;
}

// pack two f32 -> one u32 of two bf16 (lo = first)
static __device__ __forceinline__ uint pkbf(float lo, float hi) {
  return (uint)__builtin_bit_cast(unsigned short, (__bf16)lo) |
         ((uint)__builtin_bit_cast(unsigned short, (__bf16)hi) << 16);
}

// Build 2 GEMM2 B-frags (k-slices of 16) from one GEMM1 acc (32 toks).
// acc reg 4g+r holds z[tok = T + 8g + 4*lh + r][ch=lane&31 (+32*wv ch-base)].
// B-frag word j must hold toks (T + ks*16 + 8*lh + 2j, +2j+1).
static __device__ __forceinline__ void build_bfrags(const f32x16 acc, int lh,
                                                    bf16x8* bf) {
  uint wd[8];
#pragma unroll
  for (int g = 0; g < 4; ++g) {
    wd[2 * g]     = pkbf(acc[4 * g + 0], acc[4 * g + 1]);
    wd[2 * g + 1] = pkbf(acc[4 * g + 2], acc[4 * g + 3]);
  }
#pragma unroll
  for (int s = 0; s < 2; ++s) {
    uint o0 = (uint)__shfl_xor((int)wd[4 * s + 2], 32);  // partner's (T+8s*2+8 pair)
    uint o1 = (uint)__shfl_xor((int)wd[4 * s + 3], 32);
    uint o2 = (uint)__shfl_xor((int)wd[4 * s + 0], 32);
    uint o3 = (uint)__shfl_xor((int)wd[4 * s + 1], 32);
    uint w0 = lh ? o0 : wd[4 * s + 0];
    uint w1 = lh ? o1 : wd[4 * s + 1];
    uint w2 = lh ? wd[4 * s + 2] : o2;
    uint w3 = lh ? wd[4 * s + 3] : o3;
    uint4v uv = { w0, w1, w2, w3 };
    bf[s] = __builtin_bit_cast(bf16x8, uv);
  }
}

// ---------------- Main kernel ----------------
__global__ __launch_bounds__(512, 4)
void na_msa_kernel(const float* __restrict__ x,
                   const float* __restrict__ attn,
                   const __bf16* __restrict__ WT,
                   const float* __restrict__ bo,
                   float* __restrict__ out) {
  __shared__ char lds[81920];   // 2 buffers x (32KB xw + 8KB attn)

  const int t    = threadIdx.x;
  const int lane = t & 63;
  const int wvi  = t >> 6;             // wave 0..7, owns ch [32wvi, 32wvi+32)
  const int ln31 = lane & 31;
  const int lh   = lane >> 5;

  const __bf16* wtp = WT + (wvi * 32 + ln31) * 256 + 8 * lh;
  const float bv = bo[wvi * 32 + ln31];

  const int w0 = blockIdx.x * 8;

  // ---- prologue: stage window w0 into buf0 ----
  {
    const int w = w0;
    const long base = (((long)(((w >> 10) * 256) + ((w >> 5) & 31) * 8)) * 256 +
                       (w & 31) * 8) * 256;
    const float* xp = x + base;
    const float* ap = attn + (long)w * 4096;
#pragma unroll
    for (int j = 0; j < 8; ++j) {
      int gi = j * 512 + t;
      int rowblk = gi >> 9, f = gi & 511;
      f32x4 v = *(const f32x4*)(xp + rowblk * 65536 + f * 4);
      int tok = rowblk * 8 + (f >> 6);
      int ch0 = (f & 63) * 4;
      bf16x4 hv = { (__bf16)v.x, (__bf16)v.y, (__bf16)v.z, (__bf16)v.w };
      *(bf16x4*)(lds + tok * 512 + ((ch0 * 2) ^ ((tok & 31) << 4))) = hv;
    }
#pragma unroll
    for (int j = 0; j < 2; ++j) {
      int fi = j * 512 + t;
      f32x4 v = *(const f32x4*)(ap + fi * 4);
      int row = fi >> 4, k0 = (fi & 15) * 4;
      bf16x4 hv = { (__bf16)v.x, (__bf16)v.y, (__bf16)v.z, (__bf16)v.w };
      *(bf16x4*)(lds + 32768 + row * 128 + ((k0 * 2) ^ ((row & 7) << 4))) = hv;
    }
  }
  asm volatile("s_waitcnt lgkmcnt(0)" ::: "memory");
  __builtin_amdgcn_s_barrier();
  __builtin_amdgcn_sched_barrier(0);

  int cur = 0;
  for (int i = 0; i < 8; ++i) {
    const int w = w0 + i;
    char* lds_xw = lds + cur * 40960;
    char* lds_at = lds_xw + 32768;

    // ---- issue next window's global loads into registers (T14) ----
    f32x4 px0, px1, px2, px3, px4, px5, px6, px7, pa0, pa1;
    if (i < 7) {
      const int wn = w + 1;
      const long nb = (((long)(((wn >> 10) * 256) + ((wn >> 5) & 31) * 8)) * 256 +
                       (wn & 31) * 8) * 256;
      const float* xp = x + nb;
      const float* ap = attn + (long)wn * 4096;
      {
        int gi;
        gi = 0 * 512 + t; px0 = *(const f32x4*)(xp + (gi >> 9) * 65536 + (gi & 511) * 4);
        gi = 1 * 512 + t; px1 = *(const f32x4*)(xp + (gi >> 9) * 65536 + (gi & 511) * 4);
        gi = 2 * 512 + t; px2 = *(const f32x4*)(xp + (gi >> 9) * 65536 + (gi & 511) * 4);
        gi = 3 * 512 + t; px3 = *(const f32x4*)(xp + (gi >> 9) * 65536 + (gi & 511) * 4);
        gi = 4 * 512 + t; px4 = *(const f32x4*)(xp + (gi >> 9) * 65536 + (gi & 511) * 4);
        gi = 5 * 512 + t; px5 = *(const f32x4*)(xp + (gi >> 9) * 65536 + (gi & 511) * 4);
        gi = 6 * 512 + t; px6 = *(const f32x4*)(xp + (gi >> 9) * 65536 + (gi & 511) * 4);
        gi = 7 * 512 + t; px7 = *(const f32x4*)(xp + (gi >> 9) * 65536 + (gi & 511) * 4);
        pa0 = *(const f32x4*)(ap + (0 * 512 + t) * 4);
        pa1 = *(const f32x4*)(ap + (1 * 512 + t) * 4);
      }
      __builtin_amdgcn_sched_barrier(0);  // pin load issue before GEMM1
    }

    // ---- GEMM1: z[tok][ch] = xw @ W, K=256 ----
    f32x16 acc0 = {}, acc1 = {};
#pragma unroll 4
    for (int ks = 0; ks < 16; ++ks) {
      int kk = ks * 16 + 8 * lh;
      int byt0 = ln31 * 512 + ((kk * 2) ^ (ln31 << 4));
      bf16x8 a0 = *(const bf16x8*)(lds_xw + byt0);          // toks 0..31
      bf16x8 a1 = *(const bf16x8*)(lds_xw + byt0 + 16384);  // toks 32..63
      bf16x8 b0 = *(const bf16x8*)(wtp + ks * 16);          // wave's 32 ch
      acc0 = MFMA32(a0, b0, acc0);
      acc1 = MFMA32(a1, b0, acc1);
    }

    // ---- GEMM2 B-frags in-register (no zT LDS) ----
    bf16x8 bfr[4];
    build_bfrags(acc0, lh, &bfr[0]);   // ks 0,1 (toks 0..31)
    build_bfrags(acc1, lh, &bfr[2]);   // ks 2,3 (toks 32..63)

    // ---- write prefetched window to the other buffer ----
    if (i < 7) {
      char* bxw = lds + (cur ^ 1) * 40960;
      char* bat = bxw + 32768;
      f32x4 pxa[8] = { px0, px1, px2, px3, px4, px5, px6, px7 };
#pragma unroll
      for (int j = 0; j < 8; ++j) {
        int gi = j * 512 + t;
        int rowblk = gi >> 9, f = gi & 511;
        int tok = rowblk * 8 + (f >> 6);
        int ch0 = (f & 63) * 4;
        f32x4 v = pxa[j];
        bf16x4 hv = { (__bf16)v.x, (__bf16)v.y, (__bf16)v.z, (__bf16)v.w };
        *(bf16x4*)(bxw + tok * 512 + ((ch0 * 2) ^ ((tok & 31) << 4))) = hv;
      }
      {
        int fi = 0 * 512 + t;
        int row = fi >> 4, k0 = (fi & 15) * 4;
        bf16x4 hv = { (__bf16)pa0.x, (__bf16)pa0.y, (__bf16)pa0.z, (__bf16)pa0.w };
        *(bf16x4*)(bat + row * 128 + ((k0 * 2) ^ ((row & 7) << 4))) = hv;
        fi = 1 * 512 + t;
        row = fi >> 4; k0 = (fi & 15) * 4;
        bf16x4 hv1 = { (__bf16)pa1.x, (__bf16)pa1.y, (__bf16)pa1.z, (__bf16)pa1.w };
        *(bf16x4*)(bat + row * 128 + ((k0 * 2) ^ ((row & 7) << 4))) = hv1;
      }
    }

    // ---- GEMM2: out[tok][ch] = attn @ z, K=64 ----
    f32x16 o0 = {}, o1 = {};
#pragma unroll
    for (int ks = 0; ks < 4; ++ks) {
      int kk = ks * 16 + 8 * lh;
      int ab0 = ln31 * 128 + ((kk * 2) ^ ((ln31 & 7) << 4));
      bf16x8 a0 = *(const bf16x8*)(lds_at + ab0);           // out-toks 0..31
      bf16x8 a1 = *(const bf16x8*)(lds_at + ab0 + 4096);    // out-toks 32..63
      o0 = MFMA32(a0, bfr[ks], o0);
      o1 = MFMA32(a1, bfr[ks], o1);
    }

    // ---- epilogue: + bo, scatter-store window w ----
    {
      const long base = (((long)(((w >> 10) * 256) + ((w >> 5) & 31) * 8)) * 256 +
                         (w & 31) * 8) * 256;
      float* op = out + base;
      const int ch = wvi * 32 + ln31;
#pragma unroll
      for (int r = 0; r < 16; ++r) {
        int tok = (r & 3) + 8 * (r >> 2) + 4 * lh;
        op[(tok >> 3) * 65536 + (tok & 7) * 256 + ch] = o0[r] + bv;
      }
#pragma unroll
      for (int r = 0; r < 16; ++r) {
        int tok = 32 + (r & 3) + 8 * (r >> 2) + 4 * lh;
        op[(tok >> 3) * 65536 + (tok & 7) * 256 + ch] = o1[r] + bv;
      }
    }

    // ---- barrier without vmcnt drain: stores/prefetch stay in flight ----
    asm volatile("s_waitcnt lgkmcnt(0)" ::: "memory");
    __builtin_amdgcn_s_barrier();
    __builtin_amdgcn_sched_barrier(0);
    cur ^= 1;
  }
}

extern "C" void kernel_launch(void* const* d_in, const int* in_sizes, int n_in,
                              void* d_out, int out_size, void* d_ws, size_t ws_size,
                              hipStream_t stream) {
  const float* x    = (const float*)d_in[0];
  const float* attn = (const float*)d_in[1];
  const float* Wv   = (const float*)d_in[2];
  const float* Wo   = (const float*)d_in[3];
  const float* bo   = (const float*)d_in[4];
  float* out = (float*)d_out;
  __bf16* WT = (__bf16*)d_ws;   // 256*256*2 = 128 KB scratch

  wfuse_kernel<<<256, 256, 0, stream>>>(Wv, Wo, WT);
  na_msa_kernel<<<512, 512, 0, stream>>>(x, attn, WT, bo, out);
}

// Round 5
// 173.394 us; speedup vs baseline: 1.2758x; 1.2758x over previous
//
#include <hip/hip_runtime.h>
#include <hip/hip_bf16.h>

// NA Spatial MSA, fused:  out = attn @ (xw @ (Wv@Wo)) + bo
// R4b: R2 structure (4096 blocks x 1 window, 40KB LDS, single barrier) +
// launch_bounds(512,6) so staging loads batch (VGPR ~85, not 32) +
// in-register GEMM2 B-frags (pack + shfl_xor(32); no zT LDS, no 2nd barrier).

typedef __bf16 bf16x8 __attribute__((ext_vector_type(8)));
typedef __bf16 bf16x4 __attribute__((ext_vector_type(4)));
typedef float  f32x16 __attribute__((ext_vector_type(16)));
typedef float  f32x4  __attribute__((ext_vector_type(4)));
typedef unsigned int uint;
typedef uint   uint4v __attribute__((ext_vector_type(4)));

#define MFMA32(a, b, c) __builtin_amdgcn_mfma_f32_32x32x16_bf16(a, b, c, 0, 0, 0)

// ---------------- Stage 0: WT = (Wv @ Wo)^T in bf16 ----------------
__global__ void wfuse_kernel(const float* __restrict__ Wv,
                             const float* __restrict__ Wo,
                             __bf16* __restrict__ WT) {
  const int n = blockIdx.x;    // output channel (col of W)
  const int k = threadIdx.x;   // input channel  (row of W)
  const float* wvrow = Wv + k * 256;
  float acc = 0.f;
#pragma unroll 4
  for (int j = 0; j < 256; j += 4) {
    f32x4 wv = *(const f32x4*)(wvrow + j);
    acc += wv.x * Wo[(j + 0) * 256 + n];
    acc += wv.y * Wo[(j + 1) * 256 + n];
    acc += wv.z * Wo[(j + 2) * 256 + n];
    acc += wv.w * Wo[(j + 3) * 256 + n];
  }
  WT[n * 256 + k] = (__bf16)acc;
}

// pack two f32 -> one u32 of two bf16 (lo = first)
static __device__ __forceinline__ uint pkbf(float lo, float hi) {
  return (uint)__builtin_bit_cast(unsigned short, (__bf16)lo) |
         ((uint)__builtin_bit_cast(unsigned short, (__bf16)hi) << 16);
}

// Build 2 GEMM2 B-frags (k-slices of 16) from one GEMM1 acc (32 toks).
// acc reg 4g+r holds z[tok = T + 8g + 4*lh + r][ch = lane&31 (+32*wv base)].
// B-frag word j must hold toks (T + ks*16 + 8*lh + 2j, +2j+1).  (verified R3)
static __device__ __forceinline__ void build_bfrags(const f32x16 acc, int lh,
                                                    bf16x8* bf) {
  uint wd0 = pkbf(acc[0],  acc[1]);
  uint wd1 = pkbf(acc[2],  acc[3]);
  uint wd2 = pkbf(acc[4],  acc[5]);
  uint wd3 = pkbf(acc[6],  acc[7]);
  uint wd4 = pkbf(acc[8],  acc[9]);
  uint wd5 = pkbf(acc[10], acc[11]);
  uint wd6 = pkbf(acc[12], acc[13]);
  uint wd7 = pkbf(acc[14], acc[15]);
  {
    uint o0 = (uint)__shfl_xor((int)wd2, 32);
    uint o1 = (uint)__shfl_xor((int)wd3, 32);
    uint o2 = (uint)__shfl_xor((int)wd0, 32);
    uint o3 = (uint)__shfl_xor((int)wd1, 32);
    uint4v uv = { lh ? o0 : wd0, lh ? o1 : wd1,
                  lh ? wd2 : o2, lh ? wd3 : o3 };
    bf[0] = __builtin_bit_cast(bf16x8, uv);
  }
  {
    uint o0 = (uint)__shfl_xor((int)wd6, 32);
    uint o1 = (uint)__shfl_xor((int)wd7, 32);
    uint o2 = (uint)__shfl_xor((int)wd4, 32);
    uint o3 = (uint)__shfl_xor((int)wd5, 32);
    uint4v uv = { lh ? o0 : wd4, lh ? o1 : wd5,
                  lh ? wd6 : o2, lh ? wd7 : o3 };
    bf[1] = __builtin_bit_cast(bf16x8, uv);
  }
}

// ---------------- Main kernel ----------------
// LDS (40 KB): [0,32K) xw[64 tok][256 ch] bf16 swizzled; [32K,40K) attn[64][64].
__global__ __launch_bounds__(512, 6)
void na_msa_kernel(const float* __restrict__ x,
                   const float* __restrict__ attn,
                   const __bf16* __restrict__ WT,
                   const float* __restrict__ bo,
                   float* __restrict__ out) {
  __shared__ char lds[40960];
  char* lds_xw = lds;
  char* lds_at = lds + 32768;

  const int t    = threadIdx.x;
  const int lane = t & 63;
  const int wvi  = t >> 6;              // wave 0..7, owns ch [32wvi, 32wvi+32)
  const int ln31 = lane & 31;
  const int lh   = lane >> 5;           // 0 or 1 (K-half of the wave)

  const int n  = blockIdx.x;            // window id
  const int wi = n & 31;
  const int hi = (n >> 5) & 31;
  const int b  = n >> 10;
  const long base = (((long)(b * 256 + hi * 8)) * 256 + wi * 8) * 256;
  const float* xp = x + base;
  const float* ap = attn + (long)n * 4096;

  // ---- stage window x -> bf16 LDS [tok][ch], XOR swizzle (tok&31)<<4 ----
  // With VGPR cap ~85 all 10 loads issue back-to-back (1 HBM RTT).
#pragma unroll
  for (int i = 0; i < 8; ++i) {
    int gi = i * 512 + t;               // float4 index within window (0..4095)
    int rowblk = gi >> 9;               // h-row 0..7
    int f = gi & 511;                   // float4 within the 8KB row
    f32x4 v = *(const f32x4*)(xp + rowblk * 65536 + f * 4);  // coalesced
    int tok = rowblk * 8 + (f >> 6);
    int ch0 = (f & 63) * 4;
    bf16x4 hv = { (__bf16)v.x, (__bf16)v.y, (__bf16)v.z, (__bf16)v.w };
    *(bf16x4*)(lds_xw + tok * 512 + ((ch0 * 2) ^ ((tok & 31) << 4))) = hv;
  }
  // ---- stage attn -> bf16 LDS [64][64], XOR swizzle (row&7)<<4 ----
#pragma unroll
  for (int i = 0; i < 2; ++i) {
    int fi = i * 512 + t;               // float4 index 0..1023
    f32x4 v = *(const f32x4*)(ap + fi * 4);
    int row = fi >> 4;
    int k0 = (fi & 15) * 4;
    bf16x4 hv = { (__bf16)v.x, (__bf16)v.y, (__bf16)v.z, (__bf16)v.w };
    *(bf16x4*)(lds_at + row * 128 + ((k0 * 2) ^ ((row & 7) << 4))) = hv;
  }
  __syncthreads();

  // ---- GEMM1: z[tok][ch] = xw @ W, K=256. Wave owns ch [32wvi, 32wvi+32) ----
  f32x16 acc0 = {}, acc1 = {};
  const __bf16* wtp = WT + (wvi * 32 + ln31) * 256 + 8 * lh;
#pragma unroll 2
  for (int ks = 0; ks < 16; ++ks) {
    int kk = ks * 16 + 8 * lh;
    int byt0 = ln31 * 512 + ((kk * 2) ^ (ln31 << 4));
    bf16x8 a0 = *(const bf16x8*)(lds_xw + byt0);            // toks 0..31
    bf16x8 a1 = *(const bf16x8*)(lds_xw + byt0 + 16384);    // toks 32..63
    bf16x8 b0 = *(const bf16x8*)(wtp + ks * 16);            // wave's 32 ch (L2)
    acc0 = MFMA32(a0, b0, acc0);
    acc1 = MFMA32(a1, b0, acc1);
  }

  // ---- GEMM2 B-frags in-register (no zT LDS, no 2nd barrier) ----
  bf16x8 bfr[4];
  build_bfrags(acc0, lh, &bfr[0]);   // ks 0,1 (toks 0..31)
  build_bfrags(acc1, lh, &bfr[2]);   // ks 2,3 (toks 32..63)

  // ---- GEMM2: out[tok][ch] = attn @ z, K=64 ----
  f32x16 o0 = {}, o1 = {};
#pragma unroll
  for (int ks = 0; ks < 4; ++ks) {
    int kk = ks * 16 + 8 * lh;
    int ab0 = ln31 * 128 + ((kk * 2) ^ ((ln31 & 7) << 4));
    bf16x8 a0 = *(const bf16x8*)(lds_at + ab0);             // out-toks 0..31
    bf16x8 a1 = *(const bf16x8*)(lds_at + ab0 + 4096);      // out-toks 32..63
    o0 = MFMA32(a0, bfr[ks], o0);
    o1 = MFMA32(a1, bfr[ks], o1);
  }

  // ---- epilogue: + bo, scatter to (b,h,w,c). lanes 0-31 = consecutive ch ----
  float* op = out + base;
  const int ch = wvi * 32 + ln31;
  const float bv = bo[ch];
#pragma unroll
  for (int r = 0; r < 16; ++r) {
    int tok = (r & 3) + 8 * (r >> 2) + 4 * lh;              // o0: toks 0..31
    op[(tok >> 3) * 65536 + (tok & 7) * 256 + ch] = o0[r] + bv;
  }
#pragma unroll
  for (int r = 0; r < 16; ++r) {
    int tok = 32 + (r & 3) + 8 * (r >> 2) + 4 * lh;         // o1: toks 32..63
    op[(tok >> 3) * 65536 + (tok & 7) * 256 + ch] = o1[r] + bv;
  }
}

extern "C" void kernel_launch(void* const* d_in, const int* in_sizes, int n_in,
                              void* d_out, int out_size, void* d_ws, size_t ws_size,
                              hipStream_t stream) {
  const float* x    = (const float*)d_in[0];
  const float* attn = (const float*)d_in[1];
  const float* Wv   = (const float*)d_in[2];
  const float* Wo   = (const float*)d_in[3];
  const float* bo   = (const float*)d_in[4];
  float* out = (float*)d_out;
  __bf16* WT = (__bf16*)d_ws;   // 256*256*2 = 128 KB scratch

  wfuse_kernel<<<256, 256, 0, stream>>>(Wv, Wo, WT);
  na_msa_kernel<<<4096, 512, 0, stream>>>(x, attn, WT, bo, out);
}